// Round 7
// baseline (408.209 us; speedup 1.0000x reference)
//
#include <hip/hip_runtime.h>

#define BB 16
#define NN 2048
#define FF 128
#define NEG 0.01f
#define CH 128         // chunks per batch
#define CL (NN / CH)   // chunk length = 16

typedef __attribute__((ext_vector_type(8))) short short8;
typedef __attribute__((ext_vector_type(4))) float f32x4;

// float -> bf16 (RNE) and back, bit-level
__device__ __forceinline__ unsigned short f2bf_rne(float x) {
    unsigned int u = __float_as_uint(x);
    unsigned int r = u + 0x7FFFu + ((u >> 16) & 1u);
    return (unsigned short)(r >> 16);
}
__device__ __forceinline__ float bf2f(unsigned short b) {
    return __uint_as_float(((unsigned int)b) << 16);
}

// ---------------------------------------------------------------------------
// K1: Wh = h @ W via split-bf16 MFMA (hi*hi + hi*lo + lo*hi, fp32 acc),
//     fused f1 = Wh·a1, f2 = Wh·a2.
//  Block: 256 thr = 4 waves x 16 rows = 64 rows; grid 512 (2 blocks/CU).
//  W staged once/block into LDS transposed as bf16 hi/lo (64 KB exact),
//  XOR-swizzled at 16B-group granularity: byte = f*256 + ((chunk<<4) ^
//  ((f&7)<<4)) — staging writes and b128 frag reads both at baseline banking.
//  MFMA correctness: A and B frags use the SAME contiguous k-map
//  (k = ks*32 + g*8 + e); result is invariant under any k-permutation applied
//  to both operands. C/D layout (HW-verified): col=lane&15, row=(lane>>4)*4+j.
// ---------------------------------------------------------------------------
__global__ __launch_bounds__(256) void k_wh(const float* __restrict__ h,
                                            const float* __restrict__ Wg,
                                            const float* __restrict__ a,
                                            float* __restrict__ Wh,
                                            float* __restrict__ f1,
                                            float* __restrict__ f2) {
    __shared__ __align__(16) unsigned short WTs[2 * 128 * 128];  // 64 KB: [hi|lo][f][k swz]

    const int t = threadIdx.x;

    // ---- stage W -> LDS (transposed, split, swizzled) ----
    {
        const int isLo = t >> 7;          // waves 0-1: hi plane, waves 2-3: lo plane
        const int f    = t & 127;         // output column (B col)
        char* plane = (char*)WTs + isLo * 32768;
#pragma unroll
        for (int j = 0; j < 16; ++j) {    // k-chunk of 8
            short8 pk;
#pragma unroll
            for (int e = 0; e < 8; ++e) {
                int k = j * 8 + e;
                float x = Wg[k * 128 + f];            // coalesced across f
                unsigned short hb = f2bf_rne(x);
                if (isLo) hb = f2bf_rne(x - bf2f(hb));
                pk[e] = (short)hb;
            }
            unsigned int byte = f * 256 + (((unsigned)j << 4) ^ ((unsigned)(f & 7) << 4));
            *(short8*)(plane + byte) = pk;
        }
    }
    __syncthreads();

    // ---- main MFMA loop: wave computes 16 rows x 128 cols ----
    const int lane = t & 63;
    const int wid  = t >> 6;
    const int r    = lane & 15;           // A row / B col within 16-group
    const int g    = lane >> 4;           // k-group 0..3
    const int rowBase = blockIdx.x * 64 + wid * 16;
    const float* hrow = h + (size_t)(rowBase + r) * 128;

    f32x4 acc[8];
#pragma unroll
    for (int nt = 0; nt < 8; ++nt) acc[nt] = (f32x4){0.f, 0.f, 0.f, 0.f};

#pragma unroll
    for (int ks = 0; ks < 4; ++ks) {
        float4 v0 = *(const float4*)(hrow + ks * 32 + g * 8);
        float4 v1 = *(const float4*)(hrow + ks * 32 + g * 8 + 4);
        float xs[8] = {v0.x, v0.y, v0.z, v0.w, v1.x, v1.y, v1.z, v1.w};
        short8 Ahi, Alo;
#pragma unroll
        for (int e = 0; e < 8; ++e) {
            unsigned short hb = f2bf_rne(xs[e]);
            Ahi[e] = (short)hb;
            Alo[e] = (short)f2bf_rne(xs[e] - bf2f(hb));
        }
#pragma unroll
        for (int nt = 0; nt < 8; ++nt) {
            int fcol = nt * 16 + r;
            unsigned int byte = fcol * 256 +
                ((((unsigned)(ks * 4 + g)) << 4) ^ ((unsigned)(fcol & 7) << 4));
            short8 Bhi = *(const short8*)((const char*)WTs + byte);
            short8 Blo = *(const short8*)((const char*)WTs + 32768 + byte);
            acc[nt] = __builtin_amdgcn_mfma_f32_16x16x32_bf16(Ahi, Bhi, acc[nt], 0, 0, 0);
            acc[nt] = __builtin_amdgcn_mfma_f32_16x16x32_bf16(Ahi, Blo, acc[nt], 0, 0, 0);
            acc[nt] = __builtin_amdgcn_mfma_f32_16x16x32_bf16(Alo, Bhi, acc[nt], 0, 0, 0);
        }
    }

    // ---- epilogue: store Wh, fused f1/f2 ----
    float pr1[4] = {0.f, 0.f, 0.f, 0.f};
    float pr2[4] = {0.f, 0.f, 0.f, 0.f};
#pragma unroll
    for (int nt = 0; nt < 8; ++nt) {
        int col = nt * 16 + r;
        float av1 = a[col];
        float av2 = a[128 + col];
#pragma unroll
        for (int j = 0; j < 4; ++j) {
            float v = acc[nt][j];
            Wh[(size_t)(rowBase + g * 4 + j) * 128 + col] = v;   // row=(lane>>4)*4+j, col=lane&15
            pr1[j] += v * av1;
            pr2[j] += v * av2;
        }
    }
#pragma unroll
    for (int j = 0; j < 4; ++j) {
#pragma unroll
        for (int m = 1; m < 16; m <<= 1) {
            pr1[j] += __shfl_xor(pr1[j], m);
            pr2[j] += __shfl_xor(pr2[j], m);
        }
    }
    if (r == 0) {
#pragma unroll
        for (int j = 0; j < 4; ++j) {
            f1[rowBase + g * 4 + j] = pr1[j];
            f2[rowBase + g * 4 + j] = pr2[j];
        }
    }
}

// ---------------------------------------------------------------------------
// wave-level inclusive scan (width 64)
// ---------------------------------------------------------------------------
__device__ __forceinline__ float wave_incl_scan(float s, int lane) {
#pragma unroll
    for (int m = 1; m <= 32; m <<= 1) {
        float o = __shfl_up(s, m);
        if (lane >= m) s += o;
    }
    return s;
}

// ---------------------------------------------------------------------------
// Register-resident bitonic compare-exchange (partner distance j, 2<=j<=64).
// ---------------------------------------------------------------------------
template<bool WITHIDX>
__device__ __forceinline__ void cex_shfl(float& v0, float& v1, int& i0, int& i1,
                                         int tid, int j, int k) {
    const int  pj    = j >> 1;
    const bool islow = ((tid & pj) == 0);
    const bool up    = (((tid << 1) & k) == 0);
    float o0 = __shfl_xor(v0, pj);
    float o1 = __shfl_xor(v1, pj);
    int oi0 = 0, oi1 = 0;
    if (WITHIDX) { oi0 = __shfl_xor(i0, pj); oi1 = __shfl_xor(i1, pj); }
    {
        float vl = islow ? v0 : o0, vu = islow ? o0 : v0;
        if ((vl > vu) == up) { v0 = o0; if (WITHIDX) i0 = oi0; }
    }
    {
        float vl = islow ? v1 : o1, vu = islow ? o1 : v1;
        if ((vl > vu) == up) { v1 = o1; if (WITHIDX) i1 = oi1; }
    }
}

template<bool WITHIDX>
__device__ __forceinline__ void cex_intra(float& v0, float& v1, int& i0, int& i1,
                                          int tid, int k) {
    const bool up = (((tid << 1) & k) == 0);
    if ((v0 > v1) == up) {
        float tv = v0; v0 = v1; v1 = tv;
        if (WITHIDX) { int ti = i0; i0 = i1; i1 = ti; }
    }
}

// Full bitonic sort of 2048 elements, 1024 threads. Phases with j<=64 run in
// registers (shuffle exchange); only j>=128 phases touch LDS.
template<bool WITHIDX>
__device__ __forceinline__ void bitonic2048(float* sKey, int* sIdx,
                                            float v0, float v1, int i0, int i1,
                                            int tid) {
    // ---- phase A: k = 2..128 fully register-resident ----
#pragma unroll
    for (int k = 2; k <= 128; k <<= 1) {
#pragma unroll
        for (int j = 64; j >= 2; j >>= 1)
            if (j <= (k >> 1)) cex_shfl<WITHIDX>(v0, v1, i0, i1, tid, j, k);
        cex_intra<WITHIDX>(v0, v1, i0, i1, tid, k);
    }
    sKey[2 * tid] = v0; sKey[2 * tid + 1] = v1;
    if (WITHIDX) { sIdx[2 * tid] = i0; sIdx[2 * tid + 1] = i1; }

    // ---- phase B: k = 256..2048; LDS for j>=128, registers for j<=64 ----
    for (int k = 256; k <= NN; k <<= 1) {
        for (int j = k >> 1; j >= 128; j >>= 1) {
            __syncthreads();
            int mask = j - 1;
            int i   = ((tid & ~mask) << 1) | (tid & mask);
            int ixj = i | j;
            bool up = ((i & k) == 0);
            float av = sKey[i], bv = sKey[ixj];
            if ((av > bv) == up) {
                sKey[i] = bv; sKey[ixj] = av;
                if (WITHIDX) { int t2 = sIdx[i]; sIdx[i] = sIdx[ixj]; sIdx[ixj] = t2; }
            }
        }
        __syncthreads();
        v0 = sKey[2 * tid]; v1 = sKey[2 * tid + 1];
        if (WITHIDX) { i0 = sIdx[2 * tid]; i1 = sIdx[2 * tid + 1]; }
#pragma unroll
        for (int j = 64; j >= 2; j >>= 1) cex_shfl<WITHIDX>(v0, v1, i0, i1, tid, j, k);
        cex_intra<WITHIDX>(v0, v1, i0, i1, tid, k);
        sKey[2 * tid] = v0; sKey[2 * tid + 1] = v1;
        if (WITHIDX) { sIdx[2 * tid] = i0; sIdx[2 * tid + 1] = i1; }
    }
}

// ---------------------------------------------------------------------------
// K2: 32 blocks x 1024 threads. (identical to round-6 version)
// ---------------------------------------------------------------------------
__global__ __launch_bounds__(1024) void k_sort2(const float* __restrict__ f1,
                                                const float* __restrict__ f2,
                                                float* __restrict__ SF1g,
                                                float* __restrict__ PAg,
                                                float* __restrict__ SAg,
                                                float* __restrict__ SKg,
                                                int* __restrict__ PERM,
                                                int* __restrict__ KIDX,
                                                int* __restrict__ ROWS,
                                                int* __restrict__ BOFF) {
    __shared__ float sKey[NN];
    __shared__ int   sIdx[NN];
    __shared__ float wtot[16];
    __shared__ int   hist[CH];
    __shared__ int   hscan[CH + 1];
    __shared__ int   sbuf[CH];

    const int tid  = threadIdx.x;
    const int lane = tid & 63;
    const int w    = tid >> 6;
    const int b    = blockIdx.x & 15;
    const int task = blockIdx.x >> 4;

    const float* f1b = f1 + b * NN;
    const float* f2b = f2 + b * NN;

    if (task == 0) {
        float2 p = ((const float2*)f1b)[tid];
        int i0 = 0, i1 = 0;
        bitonic2048<false>(sKey, sIdx, p.x, p.y, i0, i1, tid);
    } else {
        float2 p = ((const float2*)f2b)[tid];
        bitonic2048<true>(sKey, sIdx, p.x, p.y, 2 * tid, 2 * tid + 1, tid);
    }
    __syncthreads();

    if (task == 0) {
        for (int i = tid; i < NN; i += 1024) SF1g[b * NN + i] = sKey[i];
        const size_t pbase = (size_t)b * (NN + 1);
        // ---- scan 1: exclusive prefix of exp(0.01 * sf1) ----
        {
            float a0 = expf(NEG * sKey[2 * tid]);
            float a1 = expf(NEG * sKey[2 * tid + 1]);
            float s = a0 + a1;
            float v = wave_incl_scan(s, lane);
            if (lane == 63) wtot[w] = v;
            __syncthreads();
            float off = 0.f;
#pragma unroll
            for (int ww = 0; ww < 16; ++ww) off += (ww < w) ? wtot[ww] : 0.f;
            float excl = off + v - s;
            PAg[pbase + 2 * tid]     = excl;
            PAg[pbase + 2 * tid + 1] = excl + a0;
            if (tid == 1023) PAg[pbase + NN] = off + v;
        }
        __syncthreads();   // protect wtot reuse
        // ---- scan 2: suffix sums of exp(sf1) (scan reversed array) ----
        {
            float y0 = expf(sKey[NN - 1 - 2 * tid]);
            float y1 = expf(sKey[NN - 2 - 2 * tid]);
            float s = y0 + y1;
            float v = wave_incl_scan(s, lane);
            if (lane == 63) wtot[w] = v;
            __syncthreads();
            float off = 0.f;
#pragma unroll
            for (int ww = 0; ww < 16; ++ww) off += (ww < w) ? wtot[ww] : 0.f;
            SAg[pbase + NN - 1 - 2 * tid] = off + (v - s) + y0;
            SAg[pbase + NN - 2 - 2 * tid] = off + v;
            if (tid == 0) SAg[pbase + NN] = 0.f;
        }
    } else {
        for (int i = tid; i < NN; i += 1024) {
            SKg[b * NN + i]  = sKey[i];
            PERM[b * NN + i] = sIdx[i];
        }
        if (tid < CH) hist[tid] = 0;
        __syncthreads();
        // KIDX + chunk binning histogram (sIdx reused to stash chunk ids)
        for (int i = tid; i < NN; i += 1024) {
            float tau = -f1b[i];
            int lo = 0, hi = NN;
            while (lo < hi) { int m = (lo + hi) >> 1; if (sKey[m] <= tau) lo = m + 1; else hi = m; }
            KIDX[b * NN + i] = lo;
            int c = lo / CL;
            if (c > CH - 1) c = CH - 1;   // k == NN -> last chunk (r = CL)
            sIdx[i] = c;
            atomicAdd(&hist[c], 1);
        }
        __syncthreads();
        // ---- exclusive scan of hist (Hillis-Steele over CH=128) ----
        if (tid < CH) sbuf[tid] = hist[tid];
        for (int off = 1; off < CH; off <<= 1) {
            __syncthreads();
            int v = 0;
            if (tid < CH) { v = sbuf[tid]; if (tid >= off) v += sbuf[tid - off]; }
            __syncthreads();
            if (tid < CH) sbuf[tid] = v;
        }
        __syncthreads();
        if (tid == 0) hscan[0] = 0;
        if (tid < CH) hscan[tid + 1] = sbuf[tid];
        __syncthreads();
        if (tid <= CH) BOFF[b * (CH + 1) + tid] = hscan[tid];
        if (tid < CH) hist[tid] = hscan[tid];   // reuse hist as scatter cursor
        __syncthreads();
        for (int i = tid; i < NN; i += 1024) {
            int c = sIdx[i];
            int pos = atomicAdd(&hist[c], 1);
            ROWS[b * NN + pos] = i;
        }
    }
}

// ---------------------------------------------------------------------------
// K3: per-j softmax denominators. 8 blocks per batch; only sS LDS-staged.
// ---------------------------------------------------------------------------
__global__ __launch_bounds__(256) void k_uw(const float* __restrict__ SF1g,
                                            const float* __restrict__ PAg,
                                            const float* __restrict__ SAg,
                                            const float* __restrict__ SKg,
                                            float* __restrict__ Uarr,
                                            float* __restrict__ Warr) {
    __shared__ float sS[NN];
    const int b = blockIdx.x >> 3;
    const int q = blockIdx.x & 7;
    const int tid = threadIdx.x;
    const size_t pbase = (size_t)b * (NN + 1);
    for (int i = tid; i < NN; i += 256) sS[i] = SF1g[b * NN + i];
    __syncthreads();
    const int t = q * 256 + tid;
    float f2v = SKg[b * NN + t];
    float tau = -f2v;
    int lo = 0, hi = NN;
    while (lo < hi) { int m = (lo + hi) >> 1; if (sS[m] <= tau) lo = m + 1; else hi = m; }
    float eS = expf(NEG * f2v);
    float eF = expf(f2v);
    float inv = 1.0f / (eS * PAg[pbase + lo] + eF * SAg[pbase + lo]);
    Uarr[b * NN + t] = eF * inv;
    Warr[b * NN + t] = eS * inv;
}

// ---------------------------------------------------------------------------
// K4: chunk totals (CL=16 walk per block; CH=128 chunks/batch)
// ---------------------------------------------------------------------------
__global__ __launch_bounds__(128) void k_chunk(const float* __restrict__ Wh,
                                               const float* __restrict__ Uarr,
                                               const float* __restrict__ Warr,
                                               const int* __restrict__ PERM,
                                               float* __restrict__ CU,
                                               float* __restrict__ CW) {
    int blk = blockIdx.x;               // b*CH + c
    int b = blk / CH, c = blk % CH;
    int f = threadIdx.x;
    int base = b * NN + c * CL;
    const float* Whb = Wh + (size_t)b * NN * FF;
    float aU = 0.f, aW = 0.f;
#pragma unroll
    for (int t = 0; t < CL; ++t) {
        int j = PERM[base + t];
        float uv = Uarr[base + t], wv = Warr[base + t];
        float whv = Whb[(size_t)j * FF + f];
        aU += uv * whv; aW += wv * whv;
    }
    CU[(size_t)blk * FF + f] = aU;
    CW[(size_t)blk * FF + f] = aW;
}

// ---------------------------------------------------------------------------
// K5: exclusive scan of chunk totals per (b,f); batch total -> TOT.
//  16 blocks x 1024 thr; 8 segments of 16; LDS scan of segment partials.
// ---------------------------------------------------------------------------
__global__ __launch_bounds__(1024) void k_offsets(float* __restrict__ CU,
                                                  float* __restrict__ CW,
                                                  float* __restrict__ TOT) {
    __shared__ float psU[8][FF];
    __shared__ float psW[8][FF];
    const int b   = blockIdx.x;
    const int f   = threadIdx.x & 127;
    const int seg = threadIdx.x >> 7;   // 0..7
    const size_t base = (size_t)(b * CH + seg * 16) * FF + f;

    float rU[16], rW[16];
    float sU = 0.f, sW = 0.f;
#pragma unroll
    for (int cc = 0; cc < 16; ++cc) {
        rU[cc] = CU[base + (size_t)cc * FF];
        rW[cc] = CW[base + (size_t)cc * FF];
        sU += rU[cc]; sW += rW[cc];
    }
    psU[seg][f] = sU; psW[seg][f] = sW;
    __syncthreads();

    float oU = 0.f, oW = 0.f, tU = 0.f;
#pragma unroll
    for (int s = 0; s < 8; ++s) {
        float pu = psU[s][f], pw = psW[s][f];
        if (s < seg) { oU += pu; oW += pw; }
        tU += pu;
    }
    if (seg == 0) TOT[b * FF + f] = tU;

#pragma unroll
    for (int cc = 0; cc < 16; ++cc) {
        size_t idx = base + (size_t)cc * FF;
        CU[idx] = oU; CW[idx] = oW;
        oU += rU[cc]; oW += rW[cc];
    }
}

// ---------------------------------------------------------------------------
// K6: per-chunk LDS prefix + direct output emission; empty-bucket early exit.
// ---------------------------------------------------------------------------
__global__ __launch_bounds__(128) void k_emit(const float* __restrict__ Wh,
                                              const float* __restrict__ Uarr,
                                              const float* __restrict__ Warr,
                                              const int* __restrict__ PERM,
                                              const float* __restrict__ CU,
                                              const float* __restrict__ CW,
                                              const float* __restrict__ TOT,
                                              const float* __restrict__ f1,
                                              const int* __restrict__ KIDX,
                                              const int* __restrict__ ROWS,
                                              const int* __restrict__ BOFF,
                                              float* __restrict__ out) {
    __shared__ float pU[CL + 1][FF];   // 17*128*4 = 8704 B
    __shared__ float pW[CL + 1][FF];

    const int blk = blockIdx.x;
    const int b = blk / CH, c = blk % CH;
    const int f = threadIdx.x;

    const int rb = BOFF[b * (CH + 1) + c];
    const int re = BOFF[b * (CH + 1) + c + 1];
    if (rb == re) return;              // uniform: no rows bucketed here

    float aU = CU[(size_t)blk * FF + f];
    float aW = CW[(size_t)blk * FF + f];
    const float totU = TOT[b * FF + f];

    const int base = b * NN + c * CL;
    const float* Whb = Wh + (size_t)b * NN * FF;
#pragma unroll
    for (int t = 0; t < CL; ++t) {
        pU[t][f] = aU; pW[t][f] = aW;
        int j = PERM[base + t];
        float whv = Whb[(size_t)j * FF + f];
        aU += Uarr[base + t] * whv;
        aW += Warr[base + t] * whv;
    }
    pU[CL][f] = aU; pW[CL][f] = aW;
    __syncthreads();

    for (int idx = rb; idx < re; ++idx) {
        int i = ROWS[b * NN + idx];
        int k = KIDX[b * NN + i];
        int r = k - c * CL;            // 0..CL (CL only for k==NN in last chunk)
        float f1v = f1[b * NN + i];
        float alpha = expf(NEG * f1v);
        float beta  = expf(f1v);
        out[((size_t)(b * NN + i)) * FF + f] = alpha * pW[r][f] + beta * (totU - pU[r][f]);
    }
}

// ---------------------------------------------------------------------------
extern "C" void kernel_launch(void* const* d_in, const int* in_sizes, int n_in,
                              void* d_out, int out_size, void* d_ws, size_t ws_size,
                              hipStream_t stream) {
    const float* h  = (const float*)d_in[0];
    // d_in[1] = adj — unused by the reference; never read.
    const float* W  = (const float*)d_in[2];
    const float* a  = (const float*)d_in[3];
    float* out = (float*)d_out;

    float* ws = (float*)d_ws;
    float* Wh   = ws;  ws += (size_t)BB * NN * FF;         // 4,194,304
    float* f1   = ws;  ws += BB * NN;
    float* f2   = ws;  ws += BB * NN;
    float* SF1  = ws;  ws += BB * NN;
    float* PA   = ws;  ws += BB * (NN + 1);                // 32,784
    float* SA   = ws;  ws += BB * (NN + 1);
    float* SK   = ws;  ws += BB * NN;
    float* Uarr = ws;  ws += BB * NN;
    float* Warr = ws;  ws += BB * NN;
    float* CU   = ws;  ws += (size_t)BB * CH * FF;         // 262,144
    float* CW   = ws;  ws += (size_t)BB * CH * FF;
    float* TOT  = ws;  ws += BB * FF;
    int* PERM = (int*)ws;  ws += BB * NN;
    int* KIDX = (int*)ws;  ws += BB * NN;
    int* ROWS = (int*)ws;  ws += BB * NN;
    int* BOFF = (int*)ws;  // BB*(CH+1) ints

    k_wh     <<<(BB * NN) / 64, 256, 0, stream>>>(h, W, a, Wh, f1, f2);
    k_sort2  <<<2 * BB, 1024, 0, stream>>>(f1, f2, SF1, PA, SA, SK, PERM, KIDX, ROWS, BOFF);
    k_uw     <<<BB * 8, 256, 0, stream>>>(SF1, PA, SA, SK, Uarr, Warr);
    k_chunk  <<<BB * CH, 128, 0, stream>>>(Wh, Uarr, Warr, PERM, CU, CW);
    k_offsets<<<BB, 1024, 0, stream>>>(CU, CW, TOT);
    k_emit   <<<BB * CH, 128, 0, stream>>>(Wh, Uarr, Warr, PERM, CU, CW, TOT, f1, KIDX, ROWS, BOFF, out);
}

// Round 8
// 373.215 us; speedup vs baseline: 1.0938x; 1.0938x over previous
//
#include <hip/hip_runtime.h>

#define BB 16
#define NN 2048
#define FF 128
#define NEG 0.01f
#define CH 128         // chunks per batch
#define CL (NN / CH)   // chunk length = 16

// ---------------------------------------------------------------------------
// K1: Wh = h @ W  (fp32, LDS-tiled), fused f1 = Wh·a1, f2 = Wh·a2
//  (round-6 version — at the fp32 vector-FMA roofline ~10.5 µs; MFMA-split
//   attempt in round 7 was 4x slower: 64KB-LDS occupancy + staging overhead)
// ---------------------------------------------------------------------------
__global__ __launch_bounds__(256) void k_wh(const float* __restrict__ h,
                                            const float* __restrict__ Wg,
                                            const float* __restrict__ a,
                                            float* __restrict__ Wh,
                                            float* __restrict__ f1,
                                            float* __restrict__ f2) {
    __shared__ float Ws[64 * 128];   // [k][f] half-K tile (32 KB)
    __shared__ float hsT[64 * 36];   // [k][row] transposed h tile, pad 36 (9 KB)

    const int tid  = threadIdx.x;
    const int fg   = tid & 31;        // f-group
    const int slot = tid >> 5;        // row-slot 0..7
    const int f4   = fg * 4;
    const int rowBase = blockIdx.x * 32;

    float acc[4][4];
#pragma unroll
    for (int r = 0; r < 4; ++r)
#pragma unroll
        for (int c = 0; c < 4; ++c) acc[r][c] = 0.f;

    const float4* Wg4 = (const float4*)Wg;
    const float4* hg4 = (const float4*)h;

    for (int kh = 0; kh < 128; kh += 64) {
        __syncthreads();
        for (int idx = tid; idx < 64 * 32; idx += 256) {
            int kk = idx >> 5, ff = idx & 31;
            ((float4*)Ws)[kk * 32 + ff] = Wg4[(size_t)(kh + kk) * 32 + ff];
        }
#pragma unroll
        for (int pass = 0; pass < 2; ++pass) {
            int idx = pass * 256 + tid;            // 0..511
            int kq = idx & 15, row = idx >> 4;     // kq 0..15, row 0..31
            float4 h4 = hg4[(size_t)(rowBase + row) * 32 + (kh >> 2) + kq];
            hsT[(kq * 4 + 0) * 36 + row] = h4.x;
            hsT[(kq * 4 + 1) * 36 + row] = h4.y;
            hsT[(kq * 4 + 2) * 36 + row] = h4.z;
            hsT[(kq * 4 + 3) * 36 + row] = h4.w;
        }
        __syncthreads();
#pragma unroll 8
        for (int kk = 0; kk < 64; ++kk) {
            float4 wv = *(const float4*)&Ws[kk * 128 + f4];
            float4 hv = *(const float4*)&hsT[kk * 36 + slot * 4];
            acc[0][0] += hv.x * wv.x; acc[0][1] += hv.x * wv.y; acc[0][2] += hv.x * wv.z; acc[0][3] += hv.x * wv.w;
            acc[1][0] += hv.y * wv.x; acc[1][1] += hv.y * wv.y; acc[1][2] += hv.y * wv.z; acc[1][3] += hv.y * wv.w;
            acc[2][0] += hv.z * wv.x; acc[2][1] += hv.z * wv.y; acc[2][2] += hv.z * wv.z; acc[2][3] += hv.z * wv.w;
            acc[3][0] += hv.w * wv.x; acc[3][1] += hv.w * wv.y; acc[3][2] += hv.w * wv.z; acc[3][3] += hv.w * wv.w;
        }
    }

    const float4* ag4 = (const float4*)a;
    float4 a1v = ag4[fg];
    float4 a2v = ag4[32 + fg];

#pragma unroll
    for (int r = 0; r < 4; ++r) {
        int row = rowBase + slot * 4 + r;
        float4 o; o.x = acc[r][0]; o.y = acc[r][1]; o.z = acc[r][2]; o.w = acc[r][3];
        *(float4*)&Wh[(size_t)row * 128 + f4] = o;
        float p1 = acc[r][0] * a1v.x + acc[r][1] * a1v.y + acc[r][2] * a1v.z + acc[r][3] * a1v.w;
        float p2 = acc[r][0] * a2v.x + acc[r][1] * a2v.y + acc[r][2] * a2v.z + acc[r][3] * a2v.w;
#pragma unroll
        for (int m = 16; m >= 1; m >>= 1) {
            p1 += __shfl_xor(p1, m);
            p2 += __shfl_xor(p2, m);
        }
        if (fg == 0) { f1[row] = p1; f2[row] = p2; }
    }
}

// ---------------------------------------------------------------------------
// wave-level inclusive scan (width 64)
// ---------------------------------------------------------------------------
__device__ __forceinline__ float wave_incl_scan(float s, int lane) {
#pragma unroll
    for (int m = 1; m <= 32; m <<= 1) {
        float o = __shfl_up(s, m);
        if (lane >= m) s += o;
    }
    return s;
}

// ---------------------------------------------------------------------------
// Register-resident bitonic compare-exchange (partner distance j, 2<=j<=64).
// ---------------------------------------------------------------------------
template<bool WITHIDX>
__device__ __forceinline__ void cex_shfl(float& v0, float& v1, int& i0, int& i1,
                                         int tid, int j, int k) {
    const int  pj    = j >> 1;
    const bool islow = ((tid & pj) == 0);
    const bool up    = (((tid << 1) & k) == 0);
    float o0 = __shfl_xor(v0, pj);
    float o1 = __shfl_xor(v1, pj);
    int oi0 = 0, oi1 = 0;
    if (WITHIDX) { oi0 = __shfl_xor(i0, pj); oi1 = __shfl_xor(i1, pj); }
    {
        float vl = islow ? v0 : o0, vu = islow ? o0 : v0;
        if ((vl > vu) == up) { v0 = o0; if (WITHIDX) i0 = oi0; }
    }
    {
        float vl = islow ? v1 : o1, vu = islow ? o1 : v1;
        if ((vl > vu) == up) { v1 = o1; if (WITHIDX) i1 = oi1; }
    }
}

template<bool WITHIDX>
__device__ __forceinline__ void cex_intra(float& v0, float& v1, int& i0, int& i1,
                                          int tid, int k) {
    const bool up = (((tid << 1) & k) == 0);
    if ((v0 > v1) == up) {
        float tv = v0; v0 = v1; v1 = tv;
        if (WITHIDX) { int ti = i0; i0 = i1; i1 = ti; }
    }
}

// Full bitonic sort of 2048 elements, 1024 threads. Phases with j<=64 run in
// registers (shuffle exchange); only j>=128 phases touch LDS.
template<bool WITHIDX>
__device__ __forceinline__ void bitonic2048(float* sKey, int* sIdx,
                                            float v0, float v1, int i0, int i1,
                                            int tid) {
    // ---- phase A: k = 2..128 fully register-resident ----
#pragma unroll
    for (int k = 2; k <= 128; k <<= 1) {
#pragma unroll
        for (int j = 64; j >= 2; j >>= 1)
            if (j <= (k >> 1)) cex_shfl<WITHIDX>(v0, v1, i0, i1, tid, j, k);
        cex_intra<WITHIDX>(v0, v1, i0, i1, tid, k);
    }
    sKey[2 * tid] = v0; sKey[2 * tid + 1] = v1;
    if (WITHIDX) { sIdx[2 * tid] = i0; sIdx[2 * tid + 1] = i1; }

    // ---- phase B: k = 256..2048; LDS for j>=128, registers for j<=64 ----
    for (int k = 256; k <= NN; k <<= 1) {
        for (int j = k >> 1; j >= 128; j >>= 1) {
            __syncthreads();
            int mask = j - 1;
            int i   = ((tid & ~mask) << 1) | (tid & mask);
            int ixj = i | j;
            bool up = ((i & k) == 0);
            float av = sKey[i], bv = sKey[ixj];
            if ((av > bv) == up) {
                sKey[i] = bv; sKey[ixj] = av;
                if (WITHIDX) { int t2 = sIdx[i]; sIdx[i] = sIdx[ixj]; sIdx[ixj] = t2; }
            }
        }
        __syncthreads();
        v0 = sKey[2 * tid]; v1 = sKey[2 * tid + 1];
        if (WITHIDX) { i0 = sIdx[2 * tid]; i1 = sIdx[2 * tid + 1]; }
#pragma unroll
        for (int j = 64; j >= 2; j >>= 1) cex_shfl<WITHIDX>(v0, v1, i0, i1, tid, j, k);
        cex_intra<WITHIDX>(v0, v1, i0, i1, tid, k);
        sKey[2 * tid] = v0; sKey[2 * tid + 1] = v1;
        if (WITHIDX) { sIdx[2 * tid] = i0; sIdx[2 * tid + 1] = i1; }
    }
}

// ---------------------------------------------------------------------------
// K2: 32 blocks x 1024 threads. (identical to round-6 version)
// ---------------------------------------------------------------------------
__global__ __launch_bounds__(1024) void k_sort2(const float* __restrict__ f1,
                                                const float* __restrict__ f2,
                                                float* __restrict__ SF1g,
                                                float* __restrict__ PAg,
                                                float* __restrict__ SAg,
                                                float* __restrict__ SKg,
                                                int* __restrict__ PERM,
                                                int* __restrict__ KIDX,
                                                int* __restrict__ ROWS,
                                                int* __restrict__ BOFF) {
    __shared__ float sKey[NN];
    __shared__ int   sIdx[NN];
    __shared__ float wtot[16];
    __shared__ int   hist[CH];
    __shared__ int   hscan[CH + 1];
    __shared__ int   sbuf[CH];

    const int tid  = threadIdx.x;
    const int lane = tid & 63;
    const int w    = tid >> 6;
    const int b    = blockIdx.x & 15;
    const int task = blockIdx.x >> 4;

    const float* f1b = f1 + b * NN;
    const float* f2b = f2 + b * NN;

    if (task == 0) {
        float2 p = ((const float2*)f1b)[tid];
        int i0 = 0, i1 = 0;
        bitonic2048<false>(sKey, sIdx, p.x, p.y, i0, i1, tid);
    } else {
        float2 p = ((const float2*)f2b)[tid];
        bitonic2048<true>(sKey, sIdx, p.x, p.y, 2 * tid, 2 * tid + 1, tid);
    }
    __syncthreads();

    if (task == 0) {
        for (int i = tid; i < NN; i += 1024) SF1g[b * NN + i] = sKey[i];
        const size_t pbase = (size_t)b * (NN + 1);
        // ---- scan 1: exclusive prefix of exp(0.01 * sf1) ----
        {
            float a0 = expf(NEG * sKey[2 * tid]);
            float a1 = expf(NEG * sKey[2 * tid + 1]);
            float s = a0 + a1;
            float v = wave_incl_scan(s, lane);
            if (lane == 63) wtot[w] = v;
            __syncthreads();
            float off = 0.f;
#pragma unroll
            for (int ww = 0; ww < 16; ++ww) off += (ww < w) ? wtot[ww] : 0.f;
            float excl = off + v - s;
            PAg[pbase + 2 * tid]     = excl;
            PAg[pbase + 2 * tid + 1] = excl + a0;
            if (tid == 1023) PAg[pbase + NN] = off + v;
        }
        __syncthreads();   // protect wtot reuse
        // ---- scan 2: suffix sums of exp(sf1) (scan reversed array) ----
        {
            float y0 = expf(sKey[NN - 1 - 2 * tid]);
            float y1 = expf(sKey[NN - 2 - 2 * tid]);
            float s = y0 + y1;
            float v = wave_incl_scan(s, lane);
            if (lane == 63) wtot[w] = v;
            __syncthreads();
            float off = 0.f;
#pragma unroll
            for (int ww = 0; ww < 16; ++ww) off += (ww < w) ? wtot[ww] : 0.f;
            SAg[pbase + NN - 1 - 2 * tid] = off + (v - s) + y0;
            SAg[pbase + NN - 2 - 2 * tid] = off + v;
            if (tid == 0) SAg[pbase + NN] = 0.f;
        }
    } else {
        for (int i = tid; i < NN; i += 1024) {
            SKg[b * NN + i]  = sKey[i];
            PERM[b * NN + i] = sIdx[i];
        }
        if (tid < CH) hist[tid] = 0;
        __syncthreads();
        // KIDX + chunk binning histogram (sIdx reused to stash chunk ids)
        for (int i = tid; i < NN; i += 1024) {
            float tau = -f1b[i];
            int lo = 0, hi = NN;
            while (lo < hi) { int m = (lo + hi) >> 1; if (sKey[m] <= tau) lo = m + 1; else hi = m; }
            KIDX[b * NN + i] = lo;
            int c = lo / CL;
            if (c > CH - 1) c = CH - 1;   // k == NN -> last chunk (r = CL)
            sIdx[i] = c;
            atomicAdd(&hist[c], 1);
        }
        __syncthreads();
        // ---- exclusive scan of hist (Hillis-Steele over CH=128) ----
        if (tid < CH) sbuf[tid] = hist[tid];
        for (int off = 1; off < CH; off <<= 1) {
            __syncthreads();
            int v = 0;
            if (tid < CH) { v = sbuf[tid]; if (tid >= off) v += sbuf[tid - off]; }
            __syncthreads();
            if (tid < CH) sbuf[tid] = v;
        }
        __syncthreads();
        if (tid == 0) hscan[0] = 0;
        if (tid < CH) hscan[tid + 1] = sbuf[tid];
        __syncthreads();
        if (tid <= CH) BOFF[b * (CH + 1) + tid] = hscan[tid];
        if (tid < CH) hist[tid] = hscan[tid];   // reuse hist as scatter cursor
        __syncthreads();
        for (int i = tid; i < NN; i += 1024) {
            int c = sIdx[i];
            int pos = atomicAdd(&hist[c], 1);
            ROWS[b * NN + pos] = i;
        }
    }
}

// ---------------------------------------------------------------------------
// K3 (fused k_uw + k_chunk): block (b,c) owns sorted positions
//  t in [c*16, c*16+16) — exactly one chunk, so u/w computation moves here
//  with ZERO redundancy (vs round-5's failed fusion which cut thread count).
//  Threads 0..15 compute u/w for the chunk (binary search in LDS sS; PAg/SAg
//  direct L2 hits), stash in LDS, write Uarr/Warr for k_emit; then all 128
//  threads run the unchanged gather. Same u/w values + accumulation order as
//  the separate kernels -> bit-identical CU/CW.
// ---------------------------------------------------------------------------
__global__ __launch_bounds__(128) void k_uwchunk(const float* __restrict__ SF1g,
                                                 const float* __restrict__ PAg,
                                                 const float* __restrict__ SAg,
                                                 const float* __restrict__ SKg,
                                                 const float* __restrict__ Wh,
                                                 const int* __restrict__ PERM,
                                                 float* __restrict__ Uarr,
                                                 float* __restrict__ Warr,
                                                 float* __restrict__ CU,
                                                 float* __restrict__ CW) {
    __shared__ float sS[NN];       // 8 KB
    __shared__ float sU[CL];
    __shared__ float sW[CL];

    const int blk = blockIdx.x;    // b*CH + c
    const int b = blk / CH, c = blk % CH;
    const int tid = threadIdx.x;
    const size_t pbase = (size_t)b * (NN + 1);

    for (int i = tid; i < NN; i += 128) sS[i] = SF1g[b * NN + i];
    __syncthreads();

    if (tid < CL) {
        const int t = c * CL + tid;
        float f2v = SKg[b * NN + t];
        float tau = -f2v;
        int lo = 0, hi = NN;
        while (lo < hi) { int m = (lo + hi) >> 1; if (sS[m] <= tau) lo = m + 1; else hi = m; }
        float eS = expf(NEG * f2v);
        float eF = expf(f2v);
        float inv = 1.0f / (eS * PAg[pbase + lo] + eF * SAg[pbase + lo]);
        float u = eF * inv, w = eS * inv;
        Uarr[b * NN + t] = u;
        Warr[b * NN + t] = w;
        sU[tid] = u; sW[tid] = w;
    }
    __syncthreads();

    const int f = tid;
    const int base = b * NN + c * CL;
    const float* Whb = Wh + (size_t)b * NN * FF;
    float aU = 0.f, aW = 0.f;
#pragma unroll
    for (int t = 0; t < CL; ++t) {
        int j = PERM[base + t];
        float whv = Whb[(size_t)j * FF + f];
        aU += sU[t] * whv;
        aW += sW[t] * whv;
    }
    CU[(size_t)blk * FF + f] = aU;
    CW[(size_t)blk * FF + f] = aW;
}

// ---------------------------------------------------------------------------
// K4: exclusive scan of chunk totals per (b,f); batch total -> TOT.
//  16 blocks x 1024 thr; 8 segments of 16; LDS scan of segment partials.
// ---------------------------------------------------------------------------
__global__ __launch_bounds__(1024) void k_offsets(float* __restrict__ CU,
                                                  float* __restrict__ CW,
                                                  float* __restrict__ TOT) {
    __shared__ float psU[8][FF];
    __shared__ float psW[8][FF];
    const int b   = blockIdx.x;
    const int f   = threadIdx.x & 127;
    const int seg = threadIdx.x >> 7;   // 0..7
    const size_t base = (size_t)(b * CH + seg * 16) * FF + f;

    float rU[16], rW[16];
    float sU = 0.f, sW = 0.f;
#pragma unroll
    for (int cc = 0; cc < 16; ++cc) {
        rU[cc] = CU[base + (size_t)cc * FF];
        rW[cc] = CW[base + (size_t)cc * FF];
        sU += rU[cc]; sW += rW[cc];
    }
    psU[seg][f] = sU; psW[seg][f] = sW;
    __syncthreads();

    float oU = 0.f, oW = 0.f, tU = 0.f;
#pragma unroll
    for (int s = 0; s < 8; ++s) {
        float pu = psU[s][f], pw = psW[s][f];
        if (s < seg) { oU += pu; oW += pw; }
        tU += pu;
    }
    if (seg == 0) TOT[b * FF + f] = tU;

#pragma unroll
    for (int cc = 0; cc < 16; ++cc) {
        size_t idx = base + (size_t)cc * FF;
        CU[idx] = oU; CW[idx] = oW;
        oU += rU[cc]; oW += rW[cc];
    }
}

// ---------------------------------------------------------------------------
// K5: per-chunk LDS prefix + direct output emission; empty-bucket early exit.
// ---------------------------------------------------------------------------
__global__ __launch_bounds__(128) void k_emit(const float* __restrict__ Wh,
                                              const float* __restrict__ Uarr,
                                              const float* __restrict__ Warr,
                                              const int* __restrict__ PERM,
                                              const float* __restrict__ CU,
                                              const float* __restrict__ CW,
                                              const float* __restrict__ TOT,
                                              const float* __restrict__ f1,
                                              const int* __restrict__ KIDX,
                                              const int* __restrict__ ROWS,
                                              const int* __restrict__ BOFF,
                                              float* __restrict__ out) {
    __shared__ float pU[CL + 1][FF];   // 17*128*4 = 8704 B
    __shared__ float pW[CL + 1][FF];

    const int blk = blockIdx.x;
    const int b = blk / CH, c = blk % CH;
    const int f = threadIdx.x;

    const int rb = BOFF[b * (CH + 1) + c];
    const int re = BOFF[b * (CH + 1) + c + 1];
    if (rb == re) return;              // uniform: no rows bucketed here

    float aU = CU[(size_t)blk * FF + f];
    float aW = CW[(size_t)blk * FF + f];
    const float totU = TOT[b * FF + f];

    const int base = b * NN + c * CL;
    const float* Whb = Wh + (size_t)b * NN * FF;
#pragma unroll
    for (int t = 0; t < CL; ++t) {
        pU[t][f] = aU; pW[t][f] = aW;
        int j = PERM[base + t];
        float whv = Whb[(size_t)j * FF + f];
        aU += Uarr[base + t] * whv;
        aW += Warr[base + t] * whv;
    }
    pU[CL][f] = aU; pW[CL][f] = aW;
    __syncthreads();

    for (int idx = rb; idx < re; ++idx) {
        int i = ROWS[b * NN + idx];
        int k = KIDX[b * NN + i];
        int r = k - c * CL;            // 0..CL (CL only for k==NN in last chunk)
        float f1v = f1[b * NN + i];
        float alpha = expf(NEG * f1v);
        float beta  = expf(f1v);
        out[((size_t)(b * NN + i)) * FF + f] = alpha * pW[r][f] + beta * (totU - pU[r][f]);
    }
}

// ---------------------------------------------------------------------------
extern "C" void kernel_launch(void* const* d_in, const int* in_sizes, int n_in,
                              void* d_out, int out_size, void* d_ws, size_t ws_size,
                              hipStream_t stream) {
    const float* h  = (const float*)d_in[0];
    // d_in[1] = adj — unused by the reference; never read.
    const float* W  = (const float*)d_in[2];
    const float* a  = (const float*)d_in[3];
    float* out = (float*)d_out;

    float* ws = (float*)d_ws;
    float* Wh   = ws;  ws += (size_t)BB * NN * FF;         // 4,194,304
    float* f1   = ws;  ws += BB * NN;
    float* f2   = ws;  ws += BB * NN;
    float* SF1  = ws;  ws += BB * NN;
    float* PA   = ws;  ws += BB * (NN + 1);                // 32,784
    float* SA   = ws;  ws += BB * (NN + 1);
    float* SK   = ws;  ws += BB * NN;
    float* Uarr = ws;  ws += BB * NN;
    float* Warr = ws;  ws += BB * NN;
    float* CU   = ws;  ws += (size_t)BB * CH * FF;         // 262,144
    float* CW   = ws;  ws += (size_t)BB * CH * FF;
    float* TOT  = ws;  ws += BB * FF;
    int* PERM = (int*)ws;  ws += BB * NN;
    int* KIDX = (int*)ws;  ws += BB * NN;
    int* ROWS = (int*)ws;  ws += BB * NN;
    int* BOFF = (int*)ws;  // BB*(CH+1) ints

    k_wh     <<<(BB * NN) / 32, 256, 0, stream>>>(h, W, a, Wh, f1, f2);
    k_sort2  <<<2 * BB, 1024, 0, stream>>>(f1, f2, SF1, PA, SA, SK, PERM, KIDX, ROWS, BOFF);
    k_uwchunk<<<BB * CH, 128, 0, stream>>>(SF1, PA, SA, SK, Wh, PERM, Uarr, Warr, CU, CW);
    k_offsets<<<BB, 1024, 0, stream>>>(CU, CW, TOT);
    k_emit   <<<BB * CH, 128, 0, stream>>>(Wh, Uarr, Warr, PERM, CU, CW, TOT, f1, KIDX, ROWS, BOFF, out);
}